// Round 8
// baseline (370.969 us; speedup 1.0000x reference)
//
#include <hip/hip_runtime.h>
#include <hip/hip_bf16.h>

typedef short bf16x8 __attribute__((ext_vector_type(8)));
typedef float f32x4 __attribute__((ext_vector_type(4)));
typedef float f32x16 __attribute__((ext_vector_type(16)));
typedef unsigned short ushort_t;

#define NH 16
#define HD 128
#define SEQ 2048
#define HID 2048
#define NQKV 6144
#define BATCH 2

__device__ __forceinline__ ushort_t f2bf(float x) {
    unsigned u = __builtin_bit_cast(unsigned, x);
    u = (u + 0x7fffu + ((u >> 16) & 1u)) >> 16;
    return (ushort_t)u;
}

// packed f32->bf16 pair (RTNE), low16 = lo, high16 = hi
__device__ __forceinline__ unsigned cvtpk(float lo, float hi) {
    unsigned r;
    asm("v_cvt_pk_bf16_f32 %0, %1, %2" : "=v"(r) : "v"(lo), "v"(hi));
    return r;
}

// async global->LDS, 16B per lane. LDS dest = wave-uniform base + lane*16.
__device__ __forceinline__ void gl2lds16(const ushort_t* g, ushort_t* l) {
    __builtin_amdgcn_global_load_lds(
        (__attribute__((address_space(1))) void*)(g),
        (__attribute__((address_space(3))) void*)(l), 16, 0, 0);
}

// ---------------------------------------------------------------------------
// Fused prep (one launch):
//   blocks [0, 12288):      transpose+cast w_qkv  [HID][NQKV] -> [NQKV][HID]
//   blocks [12288, 16384):  fp32->bf16 hidden states (8 elems/thread)
//   blocks [16384, 20480):  transpose+cast w_proj [HID][HID] -> [HID][HID]
// ---------------------------------------------------------------------------
__global__ __launch_bounds__(256) void prep_fused(
    const float* __restrict__ hidden, ushort_t* __restrict__ hbf,
    const float* __restrict__ wqkv, ushort_t* __restrict__ wqkvT,
    const float* __restrict__ wproj, ushort_t* __restrict__ wprojT) {
    const int bid = blockIdx.x;
    const int t = threadIdx.x;
    if (bid >= 12288 && bid < 16384) {
        int i = (bid - 12288) * 256 + t;
        float4 a0 = *(const float4*)(hidden + (size_t)i * 8);
        float4 a1 = *(const float4*)(hidden + (size_t)i * 8 + 4);
        union { ushort_t u[8]; uint4 v; } p;
        p.u[0]=f2bf(a0.x); p.u[1]=f2bf(a0.y); p.u[2]=f2bf(a0.z); p.u[3]=f2bf(a0.w);
        p.u[4]=f2bf(a1.x); p.u[5]=f2bf(a1.y); p.u[6]=f2bf(a1.z); p.u[7]=f2bf(a1.w);
        *(uint4*)(hbf + (size_t)i * 8) = p.v;
        return;
    }
    const float* w;
    ushort_t* wT;
    int N, bx, by;
    if (bid < 12288) {
        w = wqkv; wT = wqkvT; N = NQKV;
        bx = bid % 192; by = bid / 192;
    } else {
        int b2 = bid - 16384;
        w = wproj; wT = wprojT; N = HID;
        bx = b2 % 64; by = b2 / 64;
    }
    __shared__ float tile[32][33];
    const int nb = bx * 32, kb = by * 32;
    const int tx = t & 31, ty = t >> 5;
#pragma unroll
    for (int i = 0; i < 4; ++i) {
        int k = kb + ty + i * 8;
        tile[ty + i * 8][tx] = w[(size_t)k * N + nb + tx];
    }
    __syncthreads();
#pragma unroll
    for (int i = 0; i < 4; ++i) {
        int n = nb + ty + i * 8;
        wT[(size_t)n * HID + kb + tx] = f2bf(tile[tx][ty + i * 8]);
    }
}

// ---------------------------------------------------------------------------
// m97-style GEMM core: 128x128 tile, BK=64, global_load_lds(16B) staging with
// XOR-swizzled chunk order. (R4/R6: practical ceiling for this grid shape.)
// ---------------------------------------------------------------------------
#define GEMM_KLOOP(A_, BT_)                                                     \
    const int t = threadIdx.x;                                                  \
    const int w = t >> 6, lane = t & 63, lm = lane & 15, lq = lane >> 4;        \
    const int wm = (w >> 1) * 64, wn = (w & 1) * 64;                            \
    const int lrow = lane >> 3, lsw = (lane & 7) ^ lrow;                        \
    f32x4 acc[4][4] = {};                                                       \
    const ushort_t* gA = A_ + (size_t)(mb + w * 32 + lrow) * HID + lsw * 8;     \
    const ushort_t* gB = BT_ + (size_t)(nb + w * 32 + lrow) * HID + lsw * 8;    \
    for (int kb = 0; kb < HID; kb += 64) {                                      \
        __syncthreads();                                                        \
        _Pragma("unroll")                                                       \
        for (int c = 0; c < 4; ++c) {                                           \
            gl2lds16(gA + (size_t)c * 8 * HID + kb, At + (w * 256 + c * 64) * 8); \
            gl2lds16(gB + (size_t)c * 8 * HID + kb, Bt + (w * 256 + c * 64) * 8); \
        }                                                                       \
        __syncthreads();                                                        \
        _Pragma("unroll")                                                       \
        for (int kc = 0; kc < 2; ++kc) {                                        \
            const int slot = (kc * 4 + lq) ^ (lm & 7);                          \
            bf16x8 af[4], bfr[4];                                               \
            _Pragma("unroll")                                                   \
            for (int mt = 0; mt < 4; ++mt)                                      \
                af[mt] = ((const bf16x8*)At)[(wm + mt * 16 + lm) * 8 + slot];   \
            _Pragma("unroll")                                                   \
            for (int nt = 0; nt < 4; ++nt)                                      \
                bfr[nt] = ((const bf16x8*)Bt)[(wn + nt * 16 + lm) * 8 + slot];  \
            _Pragma("unroll")                                                   \
            for (int mt = 0; mt < 4; ++mt)                                      \
                _Pragma("unroll")                                               \
                for (int nt = 0; nt < 4; ++nt)                                  \
                    acc[mt][nt] = __builtin_amdgcn_mfma_f32_16x16x32_bf16(      \
                        af[mt], bfr[nt], acc[mt][nt], 0, 0, 0);                 \
        }                                                                       \
    }

// ---------------------------------------------------------------------------
// GEMM 1: qkv = hidden(bf16) @ w_qkv + b_qkv   (m97 structure)
// ---------------------------------------------------------------------------
__global__ __launch_bounds__(256) void gemm_qkv(
    const ushort_t* __restrict__ A, const ushort_t* __restrict__ BT,
    const float* __restrict__ bias,
    ushort_t* __restrict__ qbuf, ushort_t* __restrict__ kbuf,
    ushort_t* __restrict__ vTbuf) {
    __shared__ unsigned shbuf[128 * 68];  // 34KB: staging (32KB) / transpose T
    ushort_t* At = (ushort_t*)shbuf;
    ushort_t* Bt = At + 128 * 64;
    const int mb = blockIdx.x * 128;
    const int nb = blockIdx.y * 128;
    GEMM_KLOOP(A, BT)

    const int sec = nb >> 11;
    if (sec < 2) {
#pragma unroll
        for (int mt = 0; mt < 4; ++mt)
#pragma unroll
            for (int nt = 0; nt < 4; ++nt)
#pragma unroll
                for (int r = 0; r < 4; ++r) {
                    int m = mb + wm + mt * 16 + lq * 4 + r;
                    int c = nb + wn + nt * 16 + lm;
                    float val = acc[mt][nt][r] + bias[c];
                    int h = (c >> 7) & 15;
                    int d = c & 127;
                    int b = m >> 11, s = m & 2047;
                    size_t bh = (size_t)(b * NH + h);
                    ushort_t* dst = (sec == 0) ? qbuf : kbuf;
                    dst[(bh * SEQ + s) * HD + d] = f2bf(val);
                }
    } else {
        __syncthreads();
        unsigned* T = shbuf;  // [c(128)][68 uints]
#pragma unroll
        for (int mt = 0; mt < 4; ++mt)
#pragma unroll
            for (int nt = 0; nt < 4; ++nt) {
                const int cl = wn + nt * 16 + lm;       // d 0..127
                const int ml = wm + mt * 16 + lq * 4;   // s-local base
                const float bb = bias[nb + cl];
#pragma unroll
                for (int r = 0; r < 4; r += 2) {
                    unsigned pk = (unsigned)f2bf(acc[mt][nt][r] + bb) |
                                  ((unsigned)f2bf(acc[mt][nt][r + 1] + bb) << 16);
                    T[cl * 68 + ((ml + r) >> 1)] = pk;
                }
            }
        __syncthreads();
        const int d = t & 127, sh = t >> 7;
        const int b = mb >> 11, sbase = mb & 2047;
        const int hv = (nb >> 7) - 32;
        ushort_t* vrow = vTbuf + ((size_t)(b * NH + hv) * HD + d) * SEQ + sbase + sh * 64;
#pragma unroll
        for (int i = 0; i < 8; ++i)
            *(uint4*)(vrow + i * 8) = *(const uint4*)&T[d * 68 + sh * 32 + i * 4];
    }
}

// GEMM 2: out = attn(bf16) @ w_proj + b_proj -> fp32
__global__ __launch_bounds__(256) void gemm_proj(
    const ushort_t* __restrict__ A, const ushort_t* __restrict__ BT,
    const float* __restrict__ bias, float* __restrict__ out) {
    __shared__ ushort_t Abuf[128 * 64];
    __shared__ ushort_t Bbuf[128 * 64];
    ushort_t* At = Abuf;
    ushort_t* Bt = Bbuf;
    const int mb = blockIdx.x * 128;
    const int nb = blockIdx.y * 128;
    GEMM_KLOOP(A, BT)
#pragma unroll
    for (int mt = 0; mt < 4; ++mt)
#pragma unroll
        for (int nt = 0; nt < 4; ++nt)
#pragma unroll
            for (int r = 0; r < 4; ++r) {
                int m = mb + wm + mt * 16 + lq * 4 + r;
                int c = nb + wn + nt * 16 + lm;
                out[(size_t)m * HID + c] = acc[mt][nt][r] + bias[c];
            }
}

// ---------------------------------------------------------------------------
// Flash attention — R7's 32x32 swapped-operand structure (verified), with
// the ONE change: double-buffered K/V + raw s_barrier + COUNTED vmcnt(8)
// (T4). Every prior variant used __syncthreads, whose implicit
// vmcnt(0)+lgkmcnt(0) drain serialized the staging DMA with compute every
// tile. Here the 8 gl2lds for tile kt+1 stay in flight across the whole
// QK+softmax+PV of tile kt; only tile kt's loads (issued last iteration)
// are retired by vmcnt(8) at the publish barrier. Raw barriers are legal:
// LDS is written ONLY by gl2lds (P is in-register; no ds_write exists).
// Per iteration: entry s_barrier (all waves done reading buf^1) ->
// issue 8 gl2lds into buf^1 -> vmcnt(8) (tile kt resident) -> publish
// s_barrier -> compute buf. Last iteration drains vmcnt(0). LDS 64KB ->
// 2 blocks/CU.
// ---------------------------------------------------------------------------
__global__ __launch_bounds__(256) void attn_kernel(
    const ushort_t* __restrict__ qb, const ushort_t* __restrict__ kbuf,
    const ushort_t* __restrict__ vT, ushort_t* __restrict__ ob) {
    __shared__ ushort_t Ks[2][64 * 128];   // [key][d] swizzled 16B chunks
    __shared__ ushort_t Vs[2][128 * 64];   // [d][key] swizzled 16B chunks

    const int bid = blockIdx.x;
    const int x = bid & 7, g = bid >> 3;
    const int qt = 15 - (g >> 2);
    const int bh = ((g & 3) << 3) | x;
    const int qbase = qt * 128;
    const int t = threadIdx.x, w = t >> 6, lane = t & 63;
    const int l31 = lane & 31, hl = lane >> 5;

    const ushort_t* Qg = qb + (size_t)bh * SEQ * HD;
    const ushort_t* Kg = kbuf + (size_t)bh * SEQ * HD;
    const ushort_t* Vg = vT + (size_t)bh * HD * SEQ;

    const int h = bh & 15;
    const float LOG2E = 1.44269504f;
    const float slope2 = exp2f(-0.5f * (float)(h + 1)) * LOG2E;
    const float scale2 = (1.0f / 128.0f) * LOG2E;

    const int qrow = qbase + w * 32 + l31;           // this lane's q (both halves)
    const int ktd = (qbase + w * 32 + 31) >> 6;      // wave's diagonal k-tile

    // Q B-fragments: lane supplies Q[qrow][d = (2s+hl)*8 .. +8] for step s
    bf16x8 qf[8];
#pragma unroll
    for (int s = 0; s < 8; ++s) {
        uint4 qv = *(const uint4*)(Qg + (size_t)qrow * HD + (2 * s + hl) * 8);
        qf[s] = __builtin_bit_cast(bf16x8, qv);
    }

    // staging source offsets (R2-verified swizzle): LDS linear ci=i*256+t
    // holds K chunk (ks&8)|((ks&7)^(kr&7)) of key-row kr; V chunk vs^(vr&7)
    int koffs[4], voffs[4];
#pragma unroll
    for (int i = 0; i < 4; ++i) {
        int ci = i * 256 + t;
        int kr = ci >> 4, ks = ci & 15;
        int kcg = (ks & 8) | ((ks & 7) ^ (kr & 7));
        koffs[i] = kr * HD + kcg * 8;
        int vr = ci >> 3, vs = ci & 7;
        int vcg = vs ^ (vr & 7);
        voffs[i] = vr * SEQ + vcg * 8;
    }

#define ATTN_STAGE(KT, BUF)                                                   \
    {                                                                         \
        const ushort_t* Kt_ = Kg + (size_t)(KT) * 64 * HD;                    \
        const ushort_t* Vt_ = Vg + (size_t)(KT) * 64;                         \
        _Pragma("unroll")                                                     \
        for (int i = 0; i < 4; ++i) {                                         \
            gl2lds16(Kt_ + koffs[i], Ks[BUF] + (i * 256 + w * 64) * 8);       \
            gl2lds16(Vt_ + voffs[i], Vs[BUF] + (i * 256 + w * 64) * 8);       \
        }                                                                     \
    }

    float mrow = -1e30f, lrow = 0.0f;
    f32x16 O[4] = {};
    const int nkt = 2 * qt + 2;

    // prologue: issue tile 0 into buf0 (stays in flight into the loop)
    ATTN_STAGE(0, 0)

    for (int kt = 0; kt < nkt; ++kt) {
        const int cur = kt & 1;
        // entry barrier: all waves finished reading buf[cur^1] (at kt-1)
        __builtin_amdgcn_s_barrier();
        if (kt + 1 < nkt) {
            ATTN_STAGE(kt + 1, cur ^ 1)
            // retire tile kt's 8 loads; keep the new 8 in flight (T4)
            asm volatile("s_waitcnt vmcnt(8)" ::: "memory");
        } else {
            asm volatile("s_waitcnt vmcnt(0)" ::: "memory");
        }
        __builtin_amdgcn_s_barrier();  // publish buf[cur]
        __builtin_amdgcn_sched_barrier(0);

        if (kt > ktd) continue;  // wave fully masked; barriers stay uniform

        // ---- QK^T: S[key][q], 2 key-subtiles x 8 d-steps ----
        f32x16 s0 = {}, s1 = {};
        __builtin_amdgcn_s_setprio(1);
#pragma unroll
        for (int s = 0; s < 8; ++s) {
            const int c = 2 * s + hl;                      // d-chunk
            const int slot = (c & 8) | ((c & 7) ^ (l31 & 7));
            bf16x8 k0 = *(const bf16x8*)&Ks[cur][(l31 * 16 + slot) * 8];
            bf16x8 k1 = *(const bf16x8*)&Ks[cur][((32 + l31) * 16 + slot) * 8];
            s0 = __builtin_amdgcn_mfma_f32_32x32x16_bf16(k0, qf[s], s0, 0, 0, 0);
            s1 = __builtin_amdgcn_mfma_f32_32x32x16_bf16(k1, qf[s], s1, 0, 0, 0);
        }
        __builtin_amdgcn_s_setprio(0);

        // ---- scores (log2 domain) + mask on diagonal tile ----
        const float sb = slope2 * (float)(kt * 64 + 4 * hl - qrow);
        float tm = -3e38f;
        if (kt == ktd) {
#pragma unroll
            for (int r = 0; r < 16; ++r) {
                const int Cr = (r & 3) + 8 * (r >> 2);
                float v0 = s0[r] * scale2 + (sb + slope2 * (float)Cr);
                float v1 = s1[r] * scale2 + (sb + slope2 * (float)(Cr + 32));
                int k0i = kt * 64 + Cr + 4 * hl;
                v0 = (k0i <= qrow) ? v0 : -3e38f;
                v1 = (k0i + 32 <= qrow) ? v1 : -3e38f;
                s0[r] = v0; s1[r] = v1;
                tm = fmaxf(tm, fmaxf(v0, v1));
            }
        } else {
#pragma unroll
            for (int r = 0; r < 16; ++r) {
                const int Cr = (r & 3) + 8 * (r >> 2);
                float v0 = s0[r] * scale2 + (sb + slope2 * (float)Cr);
                float v1 = s1[r] * scale2 + (sb + slope2 * (float)(Cr + 32));
                s0[r] = v0; s1[r] = v1;
                tm = fmaxf(tm, fmaxf(v0, v1));
            }
        }
        tm = fmaxf(tm, __shfl_xor(tm, 32));  // partner half, same q

        // defer-max (T13, THR=8 in log2 domain)
        const bool noresc = __all(tm <= mrow + 8.0f) && (kt > 0);
        float mnew, alpha;
        if (noresc) { mnew = mrow; alpha = 1.0f; }
        else { mnew = fmaxf(mrow, tm); alpha = __builtin_amdgcn_exp2f(mrow - mnew); }
        mrow = mnew;

        // p = exp2(sc - m), per-lane row sum
        float psum = 0.0f;
#pragma unroll
        for (int r = 0; r < 16; ++r) {
            float p0 = __builtin_amdgcn_exp2f(s0[r] - mnew);
            float p1 = __builtin_amdgcn_exp2f(s1[r] - mnew);
            s0[r] = p0; s1[r] = p1;
            psum += p0 + p1;
        }
        psum += __shfl_xor(psum, 32);
        lrow = lrow * alpha + psum;

        if (!noresc) {
#pragma unroll
            for (int dt = 0; dt < 4; ++dt)
#pragma unroll
                for (int r = 0; r < 16; ++r) O[dt][r] *= alpha;
        }

        // ---- pack P to bf16 pairs: group G holds keys 8*(G&3)+32*(G>>2)+4hl+{0..3}
        unsigned c0[8], c1[8];
#pragma unroll
        for (int G = 0; G < 4; ++G) {
            c0[G]     = cvtpk(s0[4 * G + 0], s0[4 * G + 1]);
            c1[G]     = cvtpk(s0[4 * G + 2], s0[4 * G + 3]);
            c0[4 + G] = cvtpk(s1[4 * G + 0], s1[4 * G + 1]);
            c1[4 + G] = cvtpk(s1[4 * G + 2], s1[4 * G + 3]);
        }

        // ---- PV: O[d][q] += V^T x P^T, 4 k-steps x 4 d-tiles ----
        __builtin_amdgcn_s_setprio(1);
#pragma unroll
        for (int ks = 0; ks < 4; ++ks) {
            unsigned a0 = c0[2 * ks], a1 = c1[2 * ks];
            unsigned b0 = c0[2 * ks + 1], b1 = c1[2 * ks + 1];
            unsigned own0 = hl ? b0 : a0, own1 = hl ? b1 : a1;
            unsigned snd0 = hl ? a0 : b0, snd1 = hl ? a1 : b1;
            unsigned rcv0 = __shfl_xor(snd0, 32);
            unsigned rcv1 = __shfl_xor(snd1, 32);
            union { unsigned u[4]; bf16x8 v; } pf;
            pf.u[0] = hl ? rcv0 : own0;
            pf.u[1] = hl ? rcv1 : own1;
            pf.u[2] = hl ? own0 : rcv0;
            pf.u[3] = hl ? own1 : rcv1;
            const int c = 2 * ks + hl;                      // key-chunk in Vs
#pragma unroll
            for (int dt = 0; dt < 4; ++dt) {
                const int vr = dt * 32 + l31;
                const int slot = c ^ (vr & 7);
                bf16x8 vf = *(const bf16x8*)&Vs[cur][(vr * 8 + slot) * 8];
                O[dt] = __builtin_amdgcn_mfma_f32_32x32x16_bf16(vf, pf.v, O[dt], 0, 0, 0);
            }
        }
        __builtin_amdgcn_s_setprio(0);
    }

    // epilogue: O[d = dt*32 + 8*g4 + 4*hl + r3][q = qrow] / lrow
    const float lb = __builtin_amdgcn_rcpf(lrow);
    const int b = bh >> 4;
    ushort_t* orow = ob + ((size_t)(b * SEQ + qrow)) * HID + h * HD;
#pragma unroll
    for (int dt = 0; dt < 4; ++dt)
#pragma unroll
        for (int g4 = 0; g4 < 4; ++g4) {
            union { ushort_t u[4]; uint2 v; } pk;
            pk.u[0] = f2bf(O[dt][4 * g4 + 0] * lb);
            pk.u[1] = f2bf(O[dt][4 * g4 + 1] * lb);
            pk.u[2] = f2bf(O[dt][4 * g4 + 2] * lb);
            pk.u[3] = f2bf(O[dt][4 * g4 + 3] * lb);
            *(uint2*)(orow + dt * 32 + 8 * g4 + 4 * hl) = pk.v;
        }
#undef ATTN_STAGE
}

// ---------------------------------------------------------------------------
extern "C" void kernel_launch(void* const* d_in, const int* in_sizes, int n_in,
                              void* d_out, int out_size, void* d_ws, size_t ws_size,
                              hipStream_t stream) {
    const float* hidden = (const float*)d_in[0];
    const float* w_qkv = (const float*)d_in[1];
    const float* b_qkv = (const float*)d_in[2];
    const float* w_proj = (const float*)d_in[3];
    const float* b_proj = (const float*)d_in[4];
    float* out = (float*)d_out;

    char* ws = (char*)d_ws;
    size_t off = 0;
    ushort_t* wqkvT = (ushort_t*)(ws + off); off += (size_t)NQKV * HID * 2;
    ushort_t* wprojT = (ushort_t*)(ws + off); off += (size_t)HID * HID * 2;
    ushort_t* hbf = (ushort_t*)(ws + off); off += (size_t)BATCH * SEQ * HID * 2;
    ushort_t* qw = (ushort_t*)(ws + off); off += (size_t)BATCH * NH * SEQ * HD * 2;
    ushort_t* kw = (ushort_t*)(ws + off); off += (size_t)BATCH * NH * SEQ * HD * 2;
    ushort_t* vTw = (ushort_t*)(ws + off); off += (size_t)BATCH * NH * SEQ * HD * 2;
    ushort_t* attnw = (ushort_t*)(ws + off); off += (size_t)BATCH * SEQ * HID * 2;

    prep_fused<<<dim3(20480), 256, 0, stream>>>(
        hidden, hbf, w_qkv, wqkvT, w_proj, wprojT);

    gemm_qkv<<<dim3(BATCH * SEQ / 128, NQKV / 128), 256, 0, stream>>>(
        hbf, wqkvT, b_qkv, qw, kw, vTw);

    attn_kernel<<<dim3(BATCH * NH * 16), 256, 0, stream>>>(qw, kw, vTw, attnw);

    gemm_proj<<<dim3(BATCH * SEQ / 128, HID / 128), 256, 0, stream>>>(
        attnw, wprojT, b_proj, out);
}